// Round 4
// baseline (1534.978 us; speedup 1.0000x reference)
//
#include <hip/hip_runtime.h>

constexpr int F_IN  = 256;
constexpr int F_OUT = 128;

constexpr int BSHIFT = 6;
constexpr int BUCKET = 1 << BSHIFT;      // 64 dst nodes per bucket
constexpr int NSHARD = 8;                // cursor shards (~per-XCD)
constexpr int ACC_LD = F_OUT + 4;        // 132 floats: +4 pad rotates banks per row

typedef __attribute__((ext_vector_type(8))) short short8;
typedef __attribute__((ext_vector_type(4))) float f32x4;

// fp32 -> bf16 round-to-nearest-even
__device__ __forceinline__ unsigned short f2bf(float f) {
    unsigned u = __float_as_uint(f);
    u += 0x7fffu + ((u >> 16) & 1u);
    return (unsigned short)(u >> 16);
}

// ---------------------------------------------------------------------------
// Prep: Wt[n][k] = bf16(W[k][n])
// ---------------------------------------------------------------------------
__global__ void prep_wt_kernel(const float* __restrict__ W,
                               unsigned short* __restrict__ Wt)
{
    int n = blockIdx.x;      // 0..127
    int k = threadIdx.x;     // 0..255
    Wt[n * F_IN + k] = f2bf(W[k * F_OUT + n]);
}

// ---------------------------------------------------------------------------
// Stage 1: h = bf16(x @ W) via MFMA 16x16x32 bf16 (unchanged from round 3)
// ---------------------------------------------------------------------------
#define WT_LD 264

__global__ __launch_bounds__(256) void gemm_mfma_kernel(
    const float* __restrict__ x, const unsigned short* __restrict__ Wt,
    unsigned short* __restrict__ h, int n_nodes)
{
    __shared__ unsigned short Bs[F_OUT * WT_LD];   // 67.6 KB

    const int tid = threadIdx.x;
    {
        const uint4* src = (const uint4*)Wt;
        #pragma unroll
        for (int p = 0; p < 16; ++p) {
            int idx = p * 256 + tid;
            int row = idx >> 5;
            int c   = idx & 31;
            *(uint4*)&Bs[row * WT_LD + c * 8] = src[idx];
        }
    }
    __syncthreads();

    const int wave = tid >> 6;
    const int lane = tid & 63;
    const int m16  = lane & 15;
    const int quad = lane >> 4;
    const int arow = blockIdx.x * 64 + wave * 16 + m16;
    const bool inb = arow < n_nodes;

    f32x4 acc[8];
    #pragma unroll
    for (int t = 0; t < 8; ++t) acc[t] = (f32x4)(0.f);

    #pragma unroll
    for (int ks = 0; ks < 8; ++ks) {
        const int k0 = ks * 32 + quad * 8;
        short8 afrag;
        if (inb) {
            float4 a0 = *(const float4*)&x[(long long)arow * F_IN + k0];
            float4 a1 = *(const float4*)&x[(long long)arow * F_IN + k0 + 4];
            afrag[0] = (short)f2bf(a0.x); afrag[1] = (short)f2bf(a0.y);
            afrag[2] = (short)f2bf(a0.z); afrag[3] = (short)f2bf(a0.w);
            afrag[4] = (short)f2bf(a1.x); afrag[5] = (short)f2bf(a1.y);
            afrag[6] = (short)f2bf(a1.z); afrag[7] = (short)f2bf(a1.w);
        } else {
            afrag = (short8)0;
        }
        #pragma unroll
        for (int t = 0; t < 8; ++t) {
            int n = t * 16 + m16;
            short8 bfrag = *(const short8*)&Bs[n * WT_LD + k0];
            acc[t] = __builtin_amdgcn_mfma_f32_16x16x32_bf16(afrag, bfrag, acc[t], 0, 0, 0);
        }
    }

    const int rbase = blockIdx.x * 64 + wave * 16 + quad * 4;
    #pragma unroll
    for (int r = 0; r < 4; ++r) {
        int grow = rbase + r;
        if (grow < n_nodes) {
            #pragma unroll
            for (int t = 0; t < 8; ++t)
                h[(long long)grow * F_OUT + t * 16 + m16] = f2bf(acc[t][r]);
        }
    }
}

// ---------------------------------------------------------------------------
// Bucket sort (coarse): count -> scan -> append
// ---------------------------------------------------------------------------
__global__ __launch_bounds__(256) void bucket_count_kernel(
    const int* __restrict__ dst, int* __restrict__ cnt, int n_edges)
{
    int i = blockIdx.x * 256 + threadIdx.x;
    if (i < n_edges)
        atomicAdd(&cnt[(dst[i] >> BSHIFT) * NSHARD + (blockIdx.x & (NSHARD - 1))], 1);
}

// single block: scan (bucket, shard) counts lexicographically
__global__ __launch_bounds__(1024) void bucket_scan_kernel(
    const int* __restrict__ cnt, int* __restrict__ cursor,
    int* __restrict__ bucket_start, int nb)
{
    __shared__ int s[1024];
    int t = threadIdx.x;
    int b0 = 2 * t, b1 = 2 * t + 1;
    int sum0 = 0, sum1 = 0;
    if (b0 < nb) for (int j = 0; j < NSHARD; ++j) sum0 += cnt[b0 * NSHARD + j];
    if (b1 < nb) for (int j = 0; j < NSHARD; ++j) sum1 += cnt[b1 * NSHARD + j];
    s[t] = sum0 + sum1;
    __syncthreads();
    for (int off = 1; off < 1024; off <<= 1) {
        int tmp = (t >= off) ? s[t - off] : 0;
        __syncthreads();
        s[t] += tmp;
        __syncthreads();
    }
    int run = s[t] - (sum0 + sum1);   // exclusive base for this thread's pair
    if (b0 < nb) {
        bucket_start[b0] = run;
        for (int j = 0; j < NSHARD; ++j) { cursor[b0 * NSHARD + j] = run; run += cnt[b0 * NSHARD + j]; }
    }
    if (b1 < nb) {
        bucket_start[b1] = run;
        for (int j = 0; j < NSHARD; ++j) { cursor[b1 * NSHARD + j] = run; run += cnt[b1 * NSHARD + j]; }
    }
    if (t == 1023) bucket_start[nb] = s[1023];   // total = n_edges
}

__global__ __launch_bounds__(256) void bucket_append_kernel(
    const int* __restrict__ src, const int* __restrict__ dst,
    const float* __restrict__ vals, int* __restrict__ cursor,
    uint2* __restrict__ payload, int n_edges)
{
    int i = blockIdx.x * 256 + threadIdx.x;
    if (i >= n_edges) return;
    int d = dst[i];
    int b = d >> BSHIFT;
    int pos = atomicAdd(&cursor[b * NSHARD + (blockIdx.x & (NSHARD - 1))], 1);
    payload[pos] = make_uint2((unsigned)src[i] | ((unsigned)(d & (BUCKET - 1)) << 24),
                              __float_as_uint(vals[i]));
}

// ---------------------------------------------------------------------------
// Gather+accumulate: one block per bucket, fp32 accumulator in LDS.
// 16-lane group per edge: lane loads 16B (8 bf16 feats) of h-row, 8 ds_add
// with per-lane rotated feature order (spreads a group over 16 LDS banks
// instead of 4).
// ---------------------------------------------------------------------------
__global__ __launch_bounds__(256) void accum_gather_kernel(
    const unsigned short* __restrict__ h, const int* __restrict__ bucket_start,
    const uint2* __restrict__ payload, const float* __restrict__ bias,
    float* __restrict__ out, int n_nodes)
{
    __shared__ float acc[BUCKET * ACC_LD];   // 64*132*4 = 33.8 KB -> 4 blocks/CU

    const int tid = threadIdx.x;
    for (int i = tid; i < BUCKET * ACC_LD; i += 256) acc[i] = 0.f;
    __syncthreads();

    const int b     = blockIdx.x;
    const int start = bucket_start[b];
    const int end   = bucket_start[b + 1];
    const int wave  = tid >> 6;
    const int lane  = tid & 63;
    const int g     = lane >> 4;     // group 0..3 (edge within 16-pack)
    const int s16   = lane & 15;     // lane within group

    const int iters = (end - start + 15) >> 4;
    for (int it = 0; it < iters; ++it) {
        int e = start + it * 16 + wave * 4 + g;
        if (e < end) {
            uint2 p = payload[e];
            unsigned srow = p.x & 0x00FFFFFFu;
            int      drow = (int)(p.x >> 24);
            float    v    = __uint_as_float(p.y);
            uint4 hv = *(const uint4*)&h[(size_t)srow * F_OUT + s16 * 8];
            float* arow = &acc[drow * ACC_LD + s16 * 8];
            #pragma unroll
            for (int j = 0; j < 8; ++j) {
                int f = (j + s16) & 7;                     // rotated order
                unsigned uw = (f & 4) ? ((f & 2) ? hv.w : hv.z)
                                      : ((f & 2) ? hv.y : hv.x);
                float hf = __uint_as_float((f & 1) ? (uw & 0xffff0000u)
                                                   : (uw << 16));
                atomicAdd(&arow[f], v * hf);
            }
        }
    }
    __syncthreads();

    // epilogue: 64 rows x 128 feats, bias fused
    const int node0 = b << BSHIFT;
    #pragma unroll
    for (int i = tid; i < BUCKET * (F_OUT / 4); i += 256) {
        int r  = i >> 5;             // 0..63
        int c4 = (i & 31) * 4;       // 0..124
        int node = node0 + r;
        if (node < n_nodes) {
            float4 a  = *(float4*)&acc[r * ACC_LD + c4];
            float4 bi = *(const float4*)&bias[c4];
            float4 o  = make_float4(a.x + bi.x, a.y + bi.y, a.z + bi.z, a.w + bi.w);
            *(float4*)&out[(size_t)node * F_OUT + c4] = o;
        }
    }
}

// ---------------------------------------------------------------------------
extern "C" void kernel_launch(void* const* d_in, const int* in_sizes, int n_in,
                              void* d_out, int out_size, void* d_ws, size_t ws_size,
                              hipStream_t stream)
{
    const float* x     = (const float*)d_in[0];
    const int*   esrc  = (const int*)d_in[1];
    const int*   edst  = (const int*)d_in[2];
    const float* evals = (const float*)d_in[3];
    const float* W     = (const float*)d_in[4];
    const float* bias  = (const float*)d_in[5];
    float*       out   = (float*)d_out;

    const int n_nodes = in_sizes[0] / F_IN;
    const int n_edges = in_sizes[1];
    const int nb      = (n_nodes + BUCKET - 1) >> BSHIFT;   // 1563

    auto align16 = [](size_t v) { return (v + 15) & ~(size_t)15; };
    char*  base = (char*)d_ws;
    size_t off  = 0;
    unsigned short* h  = (unsigned short*)(base + off); off = align16(off + (size_t)n_nodes * F_OUT * 2);
    unsigned short* Wt = (unsigned short*)(base + off); off = align16(off + (size_t)F_IN * F_OUT * 2);
    int*   cnt          = (int*)(base + off);   off = align16(off + (size_t)nb * NSHARD * 4);
    int*   cursor       = (int*)(base + off);   off = align16(off + (size_t)nb * NSHARD * 4);
    int*   bucket_start = (int*)(base + off);   off = align16(off + (size_t)(nb + 1) * 4);
    uint2* payload      = (uint2*)(base + off); off = align16(off + (size_t)n_edges * 8);
    (void)ws_size;

    // 1) dense transform
    prep_wt_kernel<<<F_OUT, F_IN, 0, stream>>>(W, Wt);
    gemm_mfma_kernel<<<(n_nodes + 63) / 64, 256, 0, stream>>>(x, Wt, h, n_nodes);

    // 2) coarse bucket sort of edges by dst>>6
    hipMemsetAsync(cnt, 0, (size_t)nb * NSHARD * 4, stream);
    bucket_count_kernel<<<(n_edges + 255) / 256, 256, 0, stream>>>(edst, cnt, n_edges);
    bucket_scan_kernel<<<1, 1024, 0, stream>>>(cnt, cursor, bucket_start, nb);
    bucket_append_kernel<<<(n_edges + 255) / 256, 256, 0, stream>>>(
        esrc, edst, evals, cursor, payload, n_edges);

    // 3) per-bucket gather + LDS accumulate, bias fused
    accum_gather_kernel<<<nb, 256, 0, stream>>>(
        h, bucket_start, payload, bias, out, n_nodes);
}

// Round 5
// 470.206 us; speedup vs baseline: 3.2645x; 3.2645x over previous
//
#include <hip/hip_runtime.h>

constexpr int F_IN  = 256;
constexpr int F_OUT = 128;

constexpr int BSHIFT = 6;
constexpr int BUCKET = 1 << BSHIFT;      // 64 dst nodes per bucket
constexpr int NSHARD = 8;                // cursor shards (~per-XCD)

typedef __attribute__((ext_vector_type(8))) short short8;
typedef __attribute__((ext_vector_type(4))) float f32x4;

// fp32 -> bf16 round-to-nearest-even
__device__ __forceinline__ unsigned short f2bf(float f) {
    unsigned u = __float_as_uint(f);
    u += 0x7fffu + ((u >> 16) & 1u);
    return (unsigned short)(u >> 16);
}

// ---------------------------------------------------------------------------
// Prep: Wt swizzled K-major: Wt[(ks*128 + n)*32 + kk] = bf16(W[k][n]),
// k = ks*32+kk. Staging step ks then reads one contiguous 8KB block.
// ---------------------------------------------------------------------------
__global__ void prep_wt_kernel(const float* __restrict__ W,
                               unsigned short* __restrict__ Wt)
{
    int n = blockIdx.x;      // 0..127
    int k = threadIdx.x;     // 0..255
    int ks = k >> 5, kk = k & 31;
    Wt[((ks * F_OUT) + n) * 32 + kk] = f2bf(W[k * F_OUT + n]);
}

// ---------------------------------------------------------------------------
// Stage 1: h = bf16(x @ W) via MFMA 16x16x32 bf16.
// Per-K-step LDS staging (8KB slice, row stride 40 shorts -> 2-way bank
// alias only), x prefetched across the barrier. 10KB LDS -> high occupancy.
// ---------------------------------------------------------------------------
#define BS_LD 40   // 32 + 8 pad shorts; 80B row stride, 16B aligned

__global__ __launch_bounds__(256) void gemm_mfma_kernel(
    const float* __restrict__ x, const unsigned short* __restrict__ Wt,
    unsigned short* __restrict__ h, int n_nodes)
{
    __shared__ unsigned short Bs[F_OUT * BS_LD];   // 128*40*2 = 10240 B

    const int tid  = threadIdx.x;
    const int wave = tid >> 6;
    const int lane = tid & 63;
    const int m16  = lane & 15;
    const int quad = lane >> 4;          // 0..3
    const int k0q  = quad * 8;
    const int arow = blockIdx.x * 64 + wave * 16 + m16;
    const bool inb = arow < n_nodes;

    f32x4 acc[8];
    #pragma unroll
    for (int t = 0; t < 8; ++t) acc[t] = (f32x4)(0.f);

    float4 a0 = make_float4(0.f,0.f,0.f,0.f), a1 = a0;
    if (inb) {
        a0 = *(const float4*)&x[(long long)arow * F_IN + k0q];
        a1 = *(const float4*)&x[(long long)arow * F_IN + k0q + 4];
    }

    for (int ks = 0; ks < 8; ++ks) {
        // stage 8KB slice: 512 uint4 chunks, 2 per thread
        const uint4* wsrc = (const uint4*)(Wt + (size_t)ks * F_OUT * 32);
        #pragma unroll
        for (int p = 0; p < 2; ++p) {
            int c   = p * 256 + tid;        // 0..511
            int row = c >> 2;               // 0..127
            int o16 = c & 3;                // 0..3
            *(uint4*)&Bs[row * BS_LD + o16 * 8] = wsrc[c];
        }
        __syncthreads();

        // convert current afrag
        short8 af;
        af[0] = (short)f2bf(a0.x); af[1] = (short)f2bf(a0.y);
        af[2] = (short)f2bf(a0.z); af[3] = (short)f2bf(a0.w);
        af[4] = (short)f2bf(a1.x); af[5] = (short)f2bf(a1.y);
        af[6] = (short)f2bf(a1.z); af[7] = (short)f2bf(a1.w);
        if (!inb) af = (short8)0;

        // prefetch next slice of x
        if (ks < 7 && inb) {
            int kn = (ks + 1) * 32 + k0q;
            a0 = *(const float4*)&x[(long long)arow * F_IN + kn];
            a1 = *(const float4*)&x[(long long)arow * F_IN + kn + 4];
        }

        #pragma unroll
        for (int t = 0; t < 8; ++t) {
            int n = t * 16 + m16;
            short8 bf = *(const short8*)&Bs[n * BS_LD + k0q];
            acc[t] = __builtin_amdgcn_mfma_f32_16x16x32_bf16(af, bf, acc[t], 0, 0, 0);
        }
        __syncthreads();
    }

    // D layout: col = lane&15, row = quad*4 + reg
    const int rbase = blockIdx.x * 64 + wave * 16 + quad * 4;
    #pragma unroll
    for (int r = 0; r < 4; ++r) {
        int grow = rbase + r;
        if (grow < n_nodes) {
            #pragma unroll
            for (int t = 0; t < 8; ++t)
                h[(long long)grow * F_OUT + t * 16 + m16] = f2bf(acc[t][r]);
        }
    }
}

// ---------------------------------------------------------------------------
// Bucket sort (coarse): count -> scan -> append (XCD-sharded cursors)
// ---------------------------------------------------------------------------
__global__ __launch_bounds__(256) void bucket_count_kernel(
    const int* __restrict__ dst, int* __restrict__ cnt, int n_edges)
{
    int i = blockIdx.x * 256 + threadIdx.x;
    if (i < n_edges)
        atomicAdd(&cnt[(dst[i] >> BSHIFT) * NSHARD + (blockIdx.x & (NSHARD - 1))], 1);
}

__global__ __launch_bounds__(1024) void bucket_scan_kernel(
    const int* __restrict__ cnt, int* __restrict__ cursor,
    int* __restrict__ bucket_start, int nb)
{
    __shared__ int s[1024];
    int t = threadIdx.x;
    int b0 = 2 * t, b1 = 2 * t + 1;
    int sum0 = 0, sum1 = 0;
    if (b0 < nb) for (int j = 0; j < NSHARD; ++j) sum0 += cnt[b0 * NSHARD + j];
    if (b1 < nb) for (int j = 0; j < NSHARD; ++j) sum1 += cnt[b1 * NSHARD + j];
    s[t] = sum0 + sum1;
    __syncthreads();
    for (int off = 1; off < 1024; off <<= 1) {
        int tmp = (t >= off) ? s[t - off] : 0;
        __syncthreads();
        s[t] += tmp;
        __syncthreads();
    }
    int run = s[t] - (sum0 + sum1);
    if (b0 < nb) {
        bucket_start[b0] = run;
        for (int j = 0; j < NSHARD; ++j) { cursor[b0 * NSHARD + j] = run; run += cnt[b0 * NSHARD + j]; }
    }
    if (b1 < nb) {
        bucket_start[b1] = run;
        for (int j = 0; j < NSHARD; ++j) { cursor[b1 * NSHARD + j] = run; run += cnt[b1 * NSHARD + j]; }
    }
    if (t == 1023) bucket_start[nb] = s[1023];
}

__global__ __launch_bounds__(256) void bucket_append_kernel(
    const int* __restrict__ src, const int* __restrict__ dst,
    const float* __restrict__ vals, int* __restrict__ cursor,
    uint2* __restrict__ payload, int n_edges)
{
    int i = blockIdx.x * 256 + threadIdx.x;
    if (i >= n_edges) return;
    int d = dst[i];
    int b = d >> BSHIFT;
    int pos = atomicAdd(&cursor[b * NSHARD + (blockIdx.x & (NSHARD - 1))], 1);
    payload[pos] = make_uint2((unsigned)src[i] | ((unsigned)(d & (BUCKET - 1)) << 24),
                              __float_as_uint(vals[i]));
}

// ---------------------------------------------------------------------------
// Local sort: one block per bucket. 64-bin histogram -> scan -> CSR offsets
// -> scatter to sorted[] inside the bucket's contiguous region (one block =
// one XCD = dense line evictions).
// ---------------------------------------------------------------------------
__global__ __launch_bounds__(256) void local_sort_kernel(
    const uint2* __restrict__ payload, const int* __restrict__ bucket_start,
    uint2* __restrict__ sorted, int* __restrict__ offsets, int n_nodes)
{
    __shared__ int bins[BUCKET];
    __shared__ int bcur[BUCKET];

    const int b   = blockIdx.x;
    const int tid = threadIdx.x;
    const int start = bucket_start[b];
    const int end   = bucket_start[b + 1];

    if (tid < BUCKET) bins[tid] = 0;
    __syncthreads();

    for (int e = start + tid; e < end; e += 256)
        atomicAdd(&bins[payload[e].x >> 24], 1);
    __syncthreads();

    if (tid == 0) {
        int run = start;
        for (int i = 0; i < BUCKET; ++i) { bcur[i] = run; run += bins[i]; }
    }
    __syncthreads();

    if (tid < BUCKET) {
        int node = (b << BSHIFT) + tid;
        if (node < n_nodes) offsets[node] = bcur[tid];
    }
    __syncthreads();   // offsets reads of bcur must complete before scatter mutates it

    for (int e = start + tid; e < end; e += 256) {
        uint2 p = payload[e];
        int pos = atomicAdd(&bcur[p.x >> 24], 1);
        sorted[pos] = p;
    }
}

// ---------------------------------------------------------------------------
// Gather: one wave per dst node, 2 bf16 features per lane, register accum.
// ---------------------------------------------------------------------------
__global__ __launch_bounds__(256) void gather_kernel(
    const unsigned short* __restrict__ h, const int* __restrict__ offsets,
    const uint2* __restrict__ sv, const float* __restrict__ bias,
    float* __restrict__ out, int n_nodes, int n_edges)
{
    int node = blockIdx.x * 4 + (threadIdx.x >> 6);
    if (node >= n_nodes) return;
    int lane = threadIdx.x & 63;
    int f = lane * 2;

    int start = offsets[node];
    int end   = (node + 1 < n_nodes) ? offsets[node + 1] : n_edges;

    float ax = 0.f, ay = 0.f;
    int e = start;
    for (; e + 1 < end; e += 2) {
        uint2 p0 = sv[e];
        uint2 p1 = sv[e + 1];
        unsigned s0 = p0.x & 0x00FFFFFFu;
        unsigned s1 = p1.x & 0x00FFFFFFu;
        unsigned u0 = *(const unsigned*)&h[(size_t)s0 * F_OUT + f];
        unsigned u1 = *(const unsigned*)&h[(size_t)s1 * F_OUT + f];
        float v0 = __uint_as_float(p0.y);
        float v1 = __uint_as_float(p1.y);
        ax += v0 * __uint_as_float(u0 << 16) + v1 * __uint_as_float(u1 << 16);
        ay += v0 * __uint_as_float(u0 & 0xffff0000u)
            + v1 * __uint_as_float(u1 & 0xffff0000u);
    }
    if (e < end) {
        uint2 p0 = sv[e];
        unsigned s0 = p0.x & 0x00FFFFFFu;
        unsigned u0 = *(const unsigned*)&h[(size_t)s0 * F_OUT + f];
        float v0 = __uint_as_float(p0.y);
        ax += v0 * __uint_as_float(u0 << 16);
        ay += v0 * __uint_as_float(u0 & 0xffff0000u);
    }

    float2 b = *(const float2*)&bias[f];
    *(float2*)&out[(size_t)node * F_OUT + f] = make_float2(ax + b.x, ay + b.y);
}

// ---------------------------------------------------------------------------
extern "C" void kernel_launch(void* const* d_in, const int* in_sizes, int n_in,
                              void* d_out, int out_size, void* d_ws, size_t ws_size,
                              hipStream_t stream)
{
    const float* x     = (const float*)d_in[0];
    const int*   esrc  = (const int*)d_in[1];
    const int*   edst  = (const int*)d_in[2];
    const float* evals = (const float*)d_in[3];
    const float* W     = (const float*)d_in[4];
    const float* bias  = (const float*)d_in[5];
    float*       out   = (float*)d_out;

    const int n_nodes = in_sizes[0] / F_IN;
    const int n_edges = in_sizes[1];
    const int nb      = (n_nodes + BUCKET - 1) >> BSHIFT;   // 1563

    auto align16 = [](size_t v) { return (v + 15) & ~(size_t)15; };
    char*  base = (char*)d_ws;
    size_t off  = 0;
    unsigned short* h  = (unsigned short*)(base + off); off = align16(off + (size_t)n_nodes * F_OUT * 2);
    unsigned short* Wt = (unsigned short*)(base + off); off = align16(off + (size_t)F_IN * F_OUT * 2);
    int*   cnt          = (int*)(base + off);   off = align16(off + (size_t)nb * NSHARD * 4);
    int*   cursor       = (int*)(base + off);   off = align16(off + (size_t)nb * NSHARD * 4);
    int*   bucket_start = (int*)(base + off);   off = align16(off + (size_t)(nb + 1) * 4);
    int*   offsets      = (int*)(base + off);   off = align16(off + (size_t)n_nodes * 4);
    uint2* payload      = (uint2*)(base + off); off = align16(off + (size_t)n_edges * 8);
    uint2* sorted       = (uint2*)(base + off); off = align16(off + (size_t)n_edges * 8);
    (void)ws_size;

    // 1) dense transform
    prep_wt_kernel<<<F_OUT, F_IN, 0, stream>>>(W, Wt);
    gemm_mfma_kernel<<<(n_nodes + 63) / 64, 256, 0, stream>>>(x, Wt, h, n_nodes);

    // 2) coarse bucket sort by dst>>6, then per-bucket local sort -> CSR
    hipMemsetAsync(cnt, 0, (size_t)nb * NSHARD * 4, stream);
    bucket_count_kernel<<<(n_edges + 255) / 256, 256, 0, stream>>>(edst, cnt, n_edges);
    bucket_scan_kernel<<<1, 1024, 0, stream>>>(cnt, cursor, bucket_start, nb);
    bucket_append_kernel<<<(n_edges + 255) / 256, 256, 0, stream>>>(
        esrc, edst, evals, cursor, payload, n_edges);
    local_sort_kernel<<<nb, 256, 0, stream>>>(
        payload, bucket_start, sorted, offsets, n_nodes);

    // 3) gather (one wave per node, register accumulation), bias fused
    gather_kernel<<<(n_nodes + 3) / 4, 256, 0, stream>>>(
        h, offsets, sorted, bias, out, n_nodes, n_edges);
}